// Round 10
// baseline (1647.933 us; speedup 1.0000x reference)
//
#include <hip/hip_runtime.h>
#include <math.h>

// C=48, DM=24, DIN=48, DS=8, DC=4, DTR=2, B=2, D=H=W=32, L=32768
#define LL   32768
#define NCH  1024          // scan chunks per sequence
#define LC   32            // chunk length
#define BL48 3145728       // B*48*L elems == 2*48*LL
#define ROW48(g,l) (((size_t)(g)*LL + (l))*48)
#define ROW16(g,l) (((size_t)(g)*LL + (l))*16)

typedef unsigned short ushort_t;
typedef ushort_t ushort8 __attribute__((ext_vector_type(8)));
typedef ushort_t ushort4v __attribute__((ext_vector_type(4)));

__device__ __forceinline__ float sigmoidf_(float x){ return 1.0f/(1.0f+__expf(-x)); }
__device__ __forceinline__ float softplusf_(float x){ return (x > 20.0f) ? x : log1pf(__expf(x)); }
__device__ __forceinline__ ushort_t f2bf(float f){
  union { float f; unsigned u; } v; v.f = f;
  unsigned r = v.u + 0x7FFFu + ((v.u >> 16) & 1u);
  return (ushort_t)(r >> 16);
}
__device__ __forceinline__ float bf2f(ushort_t h){
  union { unsigned u; float f; } v; v.u = ((unsigned)h) << 16;
  return v.f;
}

// ---------------------------------------------------------------------------
// fp32 -> bf16 stream conversion (once, before the loop).
// ---------------------------------------------------------------------------
extern "C" __global__ void __launch_bounds__(256)
k_tobf(const float* __restrict__ in, ushort_t* __restrict__ out)
{
  const size_t i = ((size_t)blockIdx.x*256 + threadIdx.x)*4;
  float4 v = *(const float4*)(in + i);
  ushort4v o; o[0]=f2bf(v.x); o[1]=f2bf(v.y); o[2]=f2bf(v.z); o[3]=f2bf(v.w);
  *(ushort4v*)(out + i) = o;
}

// ---------------------------------------------------------------------------
// Flat fused LN + in-proj + conv(silu) + x-proj + dt + z. Wave-level channel
// split: block = 256 = 2 position-groups x 2 halves (one wave each). Each
// wave: 64 lanes <-> 64 positions (61 net, 3-lane conv halo via shuffles),
// owns d-channels [half*24, +24) -> weight addresses stay wave-uniform
// (s_load). x-proj partial xd exchanged across halves via small LDS swap.
// Outputs bf16: dtb/xcb/zb [g][pos][48], BCB [g][pos][16]; g=2*dir+b;
// backward stored at flipped pos.
// ---------------------------------------------------------------------------
extern "C" __global__ void __launch_bounds__(256, 4)
k_flat(const ushort_t* __restrict__ curb,
       const float* __restrict__ lng, const float* __restrict__ lnb,
       const float* __restrict__ in_w, const float* __restrict__ conv_w,
       const float* __restrict__ conv_b, const float* __restrict__ xproj_w,
       const float* __restrict__ dt_w, const float* __restrict__ dt_b,
       ushort_t* __restrict__ dtb, ushort_t* __restrict__ xcb,
       ushort_t* __restrict__ zb, ushort_t* __restrict__ BCB, int orient)
{
  __shared__ float sx[2][2][64][10];   // [grp][writer-half][lane][10]  10.2 KB
  const int tid  = threadIdx.x;
  const int lane = tid & 63;
  const int wv   = tid >> 6;
  const int grp  = wv >> 1;
  const int half = wv & 1;
  const int d0   = half*24;
  const int gidx = blockIdx.x*2 + grp;
  const int b    = blockIdx.y;
  const int dir  = blockIdx.z;
  const int j    = 2*orient + dir;
  const int g    = 2*dir + b;
  const int ch0  = dir*24;
  const int oth  = 24 - ch0;
  const int l    = gidx*61 - 3 + lane;
  const bool inr = (l >= 0 && l < LL);
  const bool own = inr && (dir ? (lane <= 60) : (lane >= 3));

  // ---- LN (one-pass stats; keep only this dir's 24 channels) ----
  float u[24];
  if (inr){
    const ushort_t* p = curb + (size_t)b*48*LL + l;
    float sum = 0.f, sq = 0.f;
    #pragma unroll
    for (int c2 = 0; c2 < 24; c2++){
      float vv = bf2f(p[(size_t)(ch0+c2)*LL]);
      u[c2] = vv; sum += vv; sq += vv*vv;
    }
    #pragma unroll
    for (int c2 = 0; c2 < 24; c2++){
      float vv = bf2f(p[(size_t)(oth+c2)*LL]);
      sum += vv; sq += vv*vv;
    }
    float mu = sum*(1.f/48.f);
    float var = sq*(1.f/48.f) - mu*mu;
    float rstd = rsqrtf(var + 1e-5f);
    #pragma unroll
    for (int c2 = 0; c2 < 24; c2++)
      u[c2] = (u[c2]-mu)*rstd*lng[ch0+c2] + lnb[ch0+c2];
  } else {
    #pragma unroll
    for (int c2 = 0; c2 < 24; c2++) u[c2] = 0.f;
  }

  const float* iw = in_w + j*2304;    // (96,24)
  const float* cw = conv_w + j*192;   // (48,4)
  const float* cb = conv_b + j*48;
  const float* xw = xproj_w + j*864;  // (18,48)
  const int pos = dir ? (LL-1-l) : l;

  // ---- x in-proj (own 24 ch) + conv(shfl) + silu + x-proj partials ----
  float xd[18];
  #pragma unroll
  for (int q = 0; q < 18; q++) xd[q] = 0.f;
  ushort_t* xcr = xcb + ROW48(g, pos) + d0;
  #pragma unroll
  for (int dd0 = 0; dd0 < 24; dd0 += 8){
    ushort8 oxc;
    #pragma unroll
    for (int k = 0; k < 8; k++){
      const int d = d0 + dd0 + k;
      float xzv = 0.f;
      #pragma unroll
      for (int c2 = 0; c2 < 24; c2++) xzv += u[c2]*iw[d*24+c2];
      float t1, t2, t3;
      if (dir){ t1 = __shfl_down(xzv,1); t2 = __shfl_down(xzv,2); t3 = __shfl_down(xzv,3); }
      else    { t1 = __shfl_up(xzv,1);   t2 = __shfl_up(xzv,2);   t3 = __shfl_up(xzv,3); }
      float acc = cb[d] + cw[d*4+3]*xzv + cw[d*4+2]*t1 + cw[d*4+1]*t2 + cw[d*4+0]*t3;
      acc = acc * sigmoidf_(acc);   // silu
      oxc[k] = f2bf(acc);
      #pragma unroll
      for (int q = 0; q < 18; q++) xd[q] += acc*xw[q*48+d];
    }
    if (own) *(ushort8*)(xcr + dd0) = oxc;
  }

  // ---- exchange xd partials across halves ----
  // half0 needs q in {0,1,2..9}; half1 needs q in {0,1,10..17}.
  if (half == 0){
    sx[grp][0][lane][0] = xd[0]; sx[grp][0][lane][1] = xd[1];
    #pragma unroll
    for (int k = 0; k < 8; k++) sx[grp][0][lane][2+k] = xd[10+k];
  } else {
    sx[grp][1][lane][0] = xd[0]; sx[grp][1][lane][1] = xd[1];
    #pragma unroll
    for (int k = 0; k < 8; k++) sx[grp][1][lane][2+k] = xd[2+k];
  }
  __syncthreads();
  xd[0] += sx[grp][1-half][lane][0];
  xd[1] += sx[grp][1-half][lane][1];
  if (half == 0){
    #pragma unroll
    for (int k = 0; k < 8; k++) xd[2+k]  += sx[grp][1][lane][2+k];
  } else {
    #pragma unroll
    for (int k = 0; k < 8; k++) xd[10+k] += sx[grp][0][lane][2+k];
  }

  // ---- dt (own 24 ch) ----
  const float* dw = dt_w + j*96;   // (48,2)
  const float* db = dt_b + j*48;
  ushort_t* dtr = dtb + ROW48(g, pos) + d0;
  #pragma unroll
  for (int q8 = 0; q8 < 24; q8 += 8){
    ushort8 o;
    #pragma unroll
    for (int k = 0; k < 8; k++){
      const int d = d0 + q8 + k;
      o[k] = f2bf(softplusf_(xd[0]*dw[d*2] + xd[1]*dw[d*2+1] + db[d]));
    }
    if (own) *(ushort8*)(dtr + q8) = o;
  }

  // ---- B (half0) / C (half1) ----
  if (own){
    ushort8 o;
    #pragma unroll
    for (int k = 0; k < 8; k++) o[k] = f2bf(xd[2 + half*8 + k]);
    *(ushort8*)(BCB + ROW16(g, pos) + half*8) = o;
  }

  // ---- z in-proj (own 24 outputs: e = 48+d0 .. +24) ----
  ushort_t* zr = zb + ROW48(g, pos) + d0;
  #pragma unroll
  for (int e0 = 0; e0 < 24; e0 += 8){
    ushort8 o;
    #pragma unroll
    for (int k = 0; k < 8; k++){
      const int e = 48 + d0 + e0 + k;
      float s = 0.f;
      #pragma unroll
      for (int c2 = 0; c2 < 24; c2++) s += u[c2]*iw[e*24+c2];
      o[k] = f2bf(s);
    }
    if (own) *(ushort8*)(zr + e0) = o;
  }
}

// ---------------------------------------------------------------------------
// Scan phase 1: lane = d (48 per stream), 4 streams per block (block=192).
// Per (g, chunk): P[s]=prod dA, S[s]=local scan from 0. PS layout [g][c][768]
// fp32: P at [d*8+s], S at [384+d*8+s].
// ---------------------------------------------------------------------------
extern "C" __global__ void __launch_bounds__(192)
k_scan1(const ushort_t* __restrict__ dtb, const ushort_t* __restrict__ xcb,
        const ushort_t* __restrict__ BCB, const float* __restrict__ A_log,
        float* __restrict__ PS, int orient)
{
  const int d = threadIdx.x % 48;
  const int sid = blockIdx.x*4 + threadIdx.x/48;
  const int c = sid & (NCH-1);
  const int g = sid >> 10;          // dir*2 + b
  const int dir = g >> 1;
  const float* Al = A_log + (2*orient+dir)*384 + d*8;
  float A[8], P[8], S[8];
  #pragma unroll
  for (int s = 0; s < 8; s++){ A[s] = -__expf(Al[s]); P[s]=1.f; S[s]=0.f; }
  const ushort_t* pdt = dtb + ROW48(g, c*LC) + d;
  const ushort_t* pxc = xcb + ROW48(g, c*LC) + d;
  const ushort_t* pbc = BCB + ROW16(g, c*LC);
  #pragma unroll 4
  for (int j = 0; j < LC; j++){
    float dtv = bf2f(pdt[(size_t)j*48]);
    float xcv = bf2f(pxc[(size_t)j*48]);
    ushort8 br = *(const ushort8*)(pbc + (size_t)j*16);
    float dx = dtv*xcv;
    #pragma unroll
    for (int s = 0; s < 8; s++){
      float dA = __expf(dtv*A[s]);
      P[s] *= dA;
      S[s] = S[s]*dA + dx*bf2f(br[s]);
    }
  }
  float* out = PS + ((size_t)g*NCH + c)*768 + d*8;
  *(float4*)(out)       = make_float4(P[0],P[1],P[2],P[3]);
  *(float4*)(out+4)     = make_float4(P[4],P[5],P[6],P[7]);
  *(float4*)(out+384)   = make_float4(S[0],S[1],S[2],S[3]);
  *(float4*)(out+388)   = make_float4(S[4],S[5],S[6],S[7]);
}

// ---------------------------------------------------------------------------
// Scan phase 2, parallel: 64-lane segment per (g,st) chain; lane owns 16
// chunks; Kogge-Stone affine scan across lanes; replay writes h-at-start.
// ---------------------------------------------------------------------------
extern "C" __global__ void __launch_bounds__(256)
k_scan2(float* __restrict__ PS)
{
  const int t = blockIdx.x*256 + threadIdx.x;
  const int chain = t >> 6;          // 0..1535
  const int lane  = t & 63;
  const int g  = chain / 384;
  const int st = chain % 384;
  float* base = PS + (size_t)g*NCH*768 + st;
  float P[16], S[16];
  const int c0 = lane*16;
  #pragma unroll
  for (int k = 0; k < 16; k++){
    P[k] = base[(size_t)(c0+k)*768];
    S[k] = base[(size_t)(c0+k)*768 + 384];
  }
  float Pl = 1.f, Sl = 0.f;
  #pragma unroll
  for (int k = 0; k < 16; k++){ Sl = P[k]*Sl + S[k]; Pl = P[k]*Pl; }
  float Pi = Pl, Si = Sl;
  #pragma unroll
  for (int off = 1; off < 64; off <<= 1){
    float Pp = __shfl_up(Pi, off);
    float Sp = __shfl_up(Si, off);
    if (lane >= off){ Si = Pi*Sp + Si; Pi = Pi*Pp; }
  }
  float h = __shfl_up(Si, 1);
  if (lane == 0) h = 0.f;
  #pragma unroll
  for (int k = 0; k < 16; k++){
    base[(size_t)(c0+k)*768 + 384] = h;
    h = fmaf(P[k], h, S[k]);
  }
}

// ---------------------------------------------------------------------------
// Scan phase 3 + gate + out-proj + residual. ONE direction per block
// (blockIdx.z): fwd writes channels 0..23, bwd 24..47 (disjoint planes).
// Block = 192 = 4 groups x 48 lanes; group pr scans chunk c (pos space),
// covering output l in [bx*128 + pr*32, +32). bf16 stream in/out.
// ---------------------------------------------------------------------------
extern "C" __global__ void __launch_bounds__(192)
k_scan3c(const ushort_t* __restrict__ dtb, const ushort_t* __restrict__ xcb,
         const ushort_t* __restrict__ zb, const ushort_t* __restrict__ BCB,
         const float* __restrict__ A_log, const float* __restrict__ Dp,
         const float* __restrict__ PS, const float* __restrict__ out_w,
         const ushort_t* __restrict__ resid, ushort_t* __restrict__ outp,
         int orient)
{
  __shared__ ushort_t yt[4][32][50];
  const int t = threadIdx.x;
  const int d  = t % 48;
  const int pr = t / 48;
  const int b  = blockIdx.y;
  const int dir = blockIdx.z;
  const int bx = blockIdx.x;
  const int g = 2*dir + b;
  const int j = 2*orient + dir;
  const int cf = bx*4 + pr;
  const int c  = dir ? (NCH-1-cf) : cf;

  {
    const float* Al = A_log + j*384 + d*8;
    const float* hp = PS + ((size_t)g*NCH + c)*768 + 384 + d*8;
    float A[8], h[8];
    float4 h0 = *(const float4*)(hp);
    float4 h1 = *(const float4*)(hp+4);
    h[0]=h0.x; h[1]=h0.y; h[2]=h0.z; h[3]=h0.w;
    h[4]=h1.x; h[5]=h1.y; h[6]=h1.z; h[7]=h1.w;
    #pragma unroll
    for (int s = 0; s < 8; s++) A[s] = -__expf(Al[s]);
    const float Dpd = Dp[j*48 + d];
    const ushort_t* pdt = dtb + ROW48(g, c*LC) + d;
    const ushort_t* pxc = xcb + ROW48(g, c*LC) + d;
    const ushort_t* pz  = zb  + ROW48(g, c*LC) + d;
    const ushort_t* pbc = BCB + ROW16(g, c*LC);
    for (int j2 = 0; j2 < LC; j2++){
      float dtv = bf2f(pdt[(size_t)j2*48]);
      float xcv = bf2f(pxc[(size_t)j2*48]);
      float zv  = bf2f(pz [(size_t)j2*48]);
      ushort8 br = *(const ushort8*)(pbc + (size_t)j2*16);
      ushort8 cr = *(const ushort8*)(pbc + (size_t)j2*16 + 8);
      float dx = dtv*xcv;
      float y = 0.f;
      #pragma unroll
      for (int s = 0; s < 8; s++){
        float dA = __expf(dtv*A[s]);
        h[s] = h[s]*dA + dx*bf2f(br[s]);
        y += h[s]*bf2f(cr[s]);
      }
      y += xcv*Dpd;
      int sl = dir ? (31-j2) : j2;
      yt[pr][sl][d] = f2bf(y * (zv * sigmoidf_(zv)));
    }
  }
  __syncthreads();

  // ---- out-proj (own dir's 24 channels) + residual, planar bf16 write ----
  if (t < 128){
    const int sub = t >> 5, pp = t & 31;
    const int l = bx*128 + sub*32 + pp;
    const float* ow = out_w + (size_t)j*1152;    // (24,48)
    float o[24];
    #pragma unroll
    for (int e = 0; e < 24; e++) o[e]=0.f;
    for (int dd = 0; dd < 48; dd++){
      float vv = bf2f(yt[sub][pp][dd]);
      #pragma unroll
      for (int e = 0; e < 24; e++) o[e] += vv*ow[e*48+dd];
    }
    const size_t pb = (size_t)b*48*LL + (size_t)(dir*24)*LL + l;
    #pragma unroll
    for (int e = 0; e < 24; e++){
      outp[pb + (size_t)e*LL] = f2bf(o[e] + bf2f(resid[pb + (size_t)e*LL]));
    }
  }
}

// ---------------------------------------------------------------------------
// Digit-rotation transpose (bf16 -> bf16): out[t] = in[(t%32)*1024 + t/32].
// ---------------------------------------------------------------------------
extern "C" __global__ void __launch_bounds__(256)
k_perm_bf(const ushort_t* __restrict__ in, ushort_t* __restrict__ out)
{
  __shared__ float t[32][33];
  const int q = blockIdx.y;            // plane: b*48 + c
  const ushort_t* ip = in + (size_t)q*LL;
  ushort_t* op = out + (size_t)q*LL;
  const int ab0 = blockIdx.x*32;
  const int tx = threadIdx.x & 31, ty = threadIdx.x >> 5;
  #pragma unroll
  for (int k = 0; k < 4; k++){
    int c = ty + 8*k;
    t[c][tx] = bf2f(ip[(size_t)c*1024 + ab0 + tx]);
  }
  __syncthreads();
  #pragma unroll
  for (int k = 0; k < 4; k++){
    int ab = ty + 8*k;
    op[(size_t)(ab0+ab)*32 + tx] = f2bf(t[tx][ab]);
  }
}

// ---------------------------------------------------------------------------
// Final transpose: bf16 stream + fp32 x -> fp32 out.
// ---------------------------------------------------------------------------
extern "C" __global__ void __launch_bounds__(256)
k_perm_fin(const ushort_t* __restrict__ in, const float* __restrict__ xadd,
           float* __restrict__ out)
{
  __shared__ float t[32][33];
  const int q = blockIdx.y;
  const ushort_t* ip = in + (size_t)q*LL;
  float* op = out + (size_t)q*LL;
  const int ab0 = blockIdx.x*32;
  const int tx = threadIdx.x & 31, ty = threadIdx.x >> 5;
  #pragma unroll
  for (int k = 0; k < 4; k++){
    int c = ty + 8*k;
    t[c][tx] = bf2f(ip[(size_t)c*1024 + ab0 + tx]);
  }
  __syncthreads();
  #pragma unroll
  for (int k = 0; k < 4; k++){
    int ab = ty + 8*k;
    size_t o = (size_t)(ab0+ab)*32 + tx;
    op[o] = t[tx][ab] + xadd[(size_t)q*LL + o];
  }
}

extern "C" void kernel_launch(void* const* d_in, const int* in_sizes, int n_in,
                              void* d_out, int out_size, void* d_ws, size_t ws_size,
                              hipStream_t stream)
{
  const float* x       = (const float*)d_in[0];
  const float* ln_g    = (const float*)d_in[1];
  const float* ln_b    = (const float*)d_in[2];
  const float* in_w    = (const float*)d_in[3];
  const float* conv_w  = (const float*)d_in[4];
  const float* conv_b  = (const float*)d_in[5];
  const float* xproj_w = (const float*)d_in[6];
  const float* dt_w    = (const float*)d_in[7];
  const float* dt_b    = (const float*)d_in[8];
  const float* A_log   = (const float*)d_in[9];
  const float* Dp      = (const float*)d_in[10];
  const float* out_w   = (const float*)d_in[11];
  float* out = (float*)d_out;

  char* w = (char*)d_ws;
  ushort_t* dtb  = (ushort_t*)w;  w += (size_t)4*LL*48*2;    // 12.6 MB
  ushort_t* xcb  = (ushort_t*)w;  w += (size_t)4*LL*48*2;    // 12.6 MB
  ushort_t* zbuf = (ushort_t*)w;  w += (size_t)4*LL*48*2;    // 12.6 MB
  ushort_t* BCB  = (ushort_t*)w;  w += (size_t)4*LL*16*2;    //  4.2 MB
  float*    PS   = (float*)w;     w += (size_t)4*NCH*768*4;  // 12.6 MB
  ushort_t* xb   = (ushort_t*)w;  w += (size_t)BL48*2;       //  6.3 MB
  ushort_t* soutb= (ushort_t*)w;  w += (size_t)BL48*2;       //  6.3 MB
  ushort_t* curTb= (ushort_t*)w;  w += (size_t)BL48*2;       //  6.3 MB

  k_tobf<<<dim3(BL48/1024), 256, 0, stream>>>(x, xb);

  for (int i = 0; i < 3; i++){
    const ushort_t* ip = (i == 0) ? xb : curTb;
    k_flat<<<dim3(270, 2, 2), 256, 0, stream>>>(ip, ln_g + i*48, ln_b + i*48,
        in_w, conv_w, conv_b, xproj_w, dt_w, dt_b, dtb, xcb, zbuf, BCB, i);
    k_scan1<<<dim3(NCH), 192, 0, stream>>>(dtb, xcb, BCB, A_log, PS, i);
    k_scan2<<<dim3(384), 256, 0, stream>>>(PS);
    k_scan3c<<<dim3(NCH/4, 2, 2), 192, 0, stream>>>(dtb, xcb, zbuf, BCB,
        A_log, Dp, PS, out_w, ip, soutb, i);
    if (i < 2)
      k_perm_bf<<<dim3(32, 96), 256, 0, stream>>>(soutb, curTb);
  }
  k_perm_fin<<<dim3(32, 96), 256, 0, stream>>>(soutb, x, out);
}